// Round 13
// baseline (213.488 us; speedup 1.0000x reference)
//
#include <hip/hip_runtime.h>
#include <hip/hip_bf16.h>

#define BSZ 4
#define SEQ 512
#define HID 768
#define VOC 30522
#define NPAD 30720

typedef __attribute__((ext_vector_type(8))) short short8;
typedef __attribute__((ext_vector_type(4))) float f32x4;

typedef const unsigned int __attribute__((address_space(1)))* gptr_t;
typedef unsigned int __attribute__((address_space(3)))* lptr_t;

__device__ __forceinline__ void gload_lds16(const void* g, void* l) {
    __builtin_amdgcn_global_load_lds((gptr_t)g, (lptr_t)l, 16, 0, 0);
}

// ---------------- span scans ----------------
__global__ __launch_bounds__(512) void scan_kernel(const int* __restrict__ span,
                                                   int* __restrict__ fw, int* __restrict__ bw) {
    int b = blockIdx.x;
    int j = threadIdx.x;
    __shared__ int sm[SEQ];
    __shared__ int sc[SEQ];
    int m = (span[b * SEQ + j] > -1) ? 1 : 0;
    sm[j] = m;
    __syncthreads();
    int prev = (j > 0) ? sm[j - 1] : 0;
    int nxt  = (j < SEQ - 1) ? sm[j + 1] : 0;
    int cfw = (m && !prev && j > 0) ? (j - 1) : 0;
    int cbw = (m && !nxt && j < SEQ - 1) ? (j + 1) : (SEQ - 1);

    int v = cfw;
    sc[j] = v; __syncthreads();
    for (int off = 1; off < SEQ; off <<= 1) {
        int o = (j >= off) ? sc[j - off] : 0;
        __syncthreads();
        v = max(v, o);
        sc[j] = v; __syncthreads();
    }
    fw[b * SEQ + j] = v;

    v = cbw;
    sc[j] = v; __syncthreads();
    for (int off = 1; off < SEQ; off <<= 1) {
        int o = (j + off < SEQ) ? sc[j + off] : (SEQ - 1);
        __syncthreads();
        v = min(v, o);
        sc[j] = v; __syncthreads();
    }
    bw[b * SEQ + j] = v;
}

// ---------------- merged prep: build_x (blocks 0..2047) + all transposes (rest) ----------------
#define T1_TILES (12 * 36)
#define T2_TILES (12 * 12)
#define TD_TILES (480 * 12)
#define BX_BLOCKS (BSZ * SEQ)
__global__ __launch_bounds__(256) void prep_all(const float* __restrict__ h,
                                                const int* __restrict__ span,
                                                const float* __restrict__ pe,
                                                const int* __restrict__ fw,
                                                const int* __restrict__ bw,
                                                __hip_bfloat16* __restrict__ X,
                                                const float* __restrict__ W1, __hip_bfloat16* __restrict__ W1t,
                                                const float* __restrict__ W2, __hip_bfloat16* __restrict__ W2t,
                                                const float* __restrict__ Wd, __hip_bfloat16* __restrict__ Wdt) {
    if (blockIdx.x < BX_BLOCKS) {
        int r = blockIdx.x;
        int b = r >> 9, s = r & (SEQ - 1);
        float mf = (span[r] > -1) ? 1.f : 0.f;
        int f = fw[r], w = bw[r];
        const float* hf = h + ((size_t)b * SEQ + f) * HID;
        const float* hb = h + ((size_t)b * SEQ + w) * HID;
        const float* pp = pe + (size_t)s * HID;
        __hip_bfloat16* xr = X + (size_t)r * (3 * HID);
        for (int u = threadIdx.x; u < 3 * HID / 2; u += 256) {
            int seg = u / (HID / 2);
            int c = (u % (HID / 2)) * 2;
            const float* src = (seg == 0) ? hf : (seg == 1) ? hb : pp;
            float2 v = *(const float2*)&src[c];
            __hip_bfloat16 lo = __float2bfloat16(v.x * mf);
            __hip_bfloat16 hi = __float2bfloat16(v.y * mf);
            unsigned int pk = ((unsigned int)*(unsigned short*)&hi << 16) | *(unsigned short*)&lo;
            *(unsigned int*)&xr[seg * HID + c] = pk;
        }
        return;
    }
    int flat = blockIdx.x - BX_BLOCKS;
    const float* W; __hip_bfloat16* Wt; int K, N, tx_tiles, idx;
    if (flat < T1_TILES)                { W = W1; Wt = W1t; K = 3 * HID; N = HID; tx_tiles = 12;  idx = flat; }
    else if (flat < T1_TILES + T2_TILES){ W = W2; Wt = W2t; K = HID;     N = HID; tx_tiles = 12;  idx = flat - T1_TILES; }
    else                                { W = Wd; Wt = Wdt; K = HID;     N = VOC; tx_tiles = 480; idx = flat - T1_TILES - T2_TILES; }
    int n0 = (idx % tx_tiles) * 64, k0 = (idx / tx_tiles) * 64;

    __shared__ float t[64][67];
    int tx = threadIdx.x & 31, ty = threadIdx.x >> 5;
    #pragma unroll
    for (int i = 0; i < 64; i += 8) {
        #pragma unroll
        for (int jx = 0; jx < 64; jx += 32) {
            int k = k0 + ty + i, n = n0 + tx + jx;
            t[ty + i][tx + jx] = (n < N) ? W[(size_t)k * N + n] : 0.f;
        }
    }
    __syncthreads();
    #pragma unroll
    for (int i = 0; i < 8; i++) {
        int nn = ty + i * 8;
        int n = n0 + nn;
        float a = t[tx * 2][nn], b = t[tx * 2 + 1][nn];
        __hip_bfloat16 ba = __float2bfloat16(a), bb = __float2bfloat16(b);
        unsigned int pk = ((unsigned int)*(unsigned short*)&bb << 16) | *(unsigned short*)&ba;
        *(unsigned int*)&Wt[(size_t)n * K + k0 + tx * 2] = pk;
    }
}

// ---------------- sum(P split-K parts)+bias, exact gelu, layernorm -> bf16 ----------------
template<int P>
__global__ __launch_bounds__(256) void gelu_ln(const float* __restrict__ Y, size_t ystride,
                                               const float* __restrict__ bias,
                                               const float* __restrict__ g,
                                               const float* __restrict__ be,
                                               __hip_bfloat16* __restrict__ out) {
    int r = blockIdx.x;
    float z[3];
    float s1 = 0.f, s2 = 0.f;
    #pragma unroll
    for (int i = 0; i < 3; i++) {
        int c = threadIdx.x + i * 256;
        float x = bias[c];
        #pragma unroll
        for (int p = 0; p < P; p++)
            x += Y[p * ystride + (size_t)r * HID + c];
        float zz = 0.5f * x * (1.f + erff(x * 0.70710678118654752f));
        z[i] = zz; s1 += zz; s2 += zz * zz;
    }
    #pragma unroll
    for (int off = 32; off; off >>= 1) {
        s1 += __shfl_down(s1, off);
        s2 += __shfl_down(s2, off);
    }
    __shared__ float p1[4], p2[4];
    int w = threadIdx.x >> 6, lane = threadIdx.x & 63;
    if (lane == 0) { p1[w] = s1; p2[w] = s2; }
    __syncthreads();
    s1 = p1[0] + p1[1] + p1[2] + p1[3];
    s2 = p2[0] + p2[1] + p2[2] + p2[3];
    float mu = s1 * (1.f / HID);
    float var = s2 * (1.f / HID) - mu * mu;
    float rs = rsqrtf(var + 1e-12f);
    __hip_bfloat16* o = out + (size_t)r * HID;
    #pragma unroll
    for (int i = 0; i < 3; i++) {
        int c = threadIdx.x + i * 256;
        o[c] = __float2bfloat16((z[i] - mu) * rs * g[c] + be[c]);
    }
}

// ---------------- 128x128 split-K GEMM, 2-phase schedule (R10 exact) ----------------
__global__ __launch_bounds__(256, 2) void gemm_splitk(const __hip_bfloat16* __restrict__ A,
                                                      const __hip_bfloat16* __restrict__ Bt,
                                                      float* __restrict__ C,
                                                      int lda, int Klen, int ldc, size_t cstride) {
    __shared__ char lds[65536];
    int bx = blockIdx.x, by = blockIdx.y;
    int koff = blockIdx.z * Klen;
    float* Cz = C + (size_t)blockIdx.z * cstride;

    int tid = threadIdx.x;
    int lane = tid & 63;
    int w = tid >> 6;
    int wr = w >> 1, wc = w & 1;

    int r0 = tid >> 3;
    int swz8 = (((tid & 7) ^ (r0 & 7)) << 3);
    const __hip_bfloat16* Abase = A + (size_t)(by * 128) * lda + koff;
    const __hip_bfloat16* Bbase = Bt + (size_t)(bx * 128) * lda + koff;
    size_t arow = (size_t)r0 * lda + swz8;
    int ldsw = tid * 16;

    int rxor = (lane & 7) << 4;
    int rcol = (lane >> 4) * 16;
    int rc0 = rcol ^ rxor;
    int rc1 = (64 + rcol) ^ rxor;
    int aoff = (wr * 64 + (lane & 15)) * 128;
    int boff = 16384 + (wc * 64 + (lane & 15)) * 128;

    f32x4 acc[4][4] = {};
    int nt = Klen >> 6;

#define STQ1(t) do { const __hip_bfloat16* gg = Abase + (t) * 64; \
        char* dd = lds + ((t) & 1) * 32768 + ldsw; \
        gload_lds16(gg + arow, dd); gload_lds16(gg + arow + (size_t)32 * lda, dd + 4096); } while (0)
#define STQ2(t) do { const __hip_bfloat16* gg = Abase + (t) * 64 + (size_t)64 * lda; \
        char* dd = lds + ((t) & 1) * 32768 + 8192 + ldsw; \
        gload_lds16(gg + arow, dd); gload_lds16(gg + arow + (size_t)32 * lda, dd + 4096); } while (0)
#define STQ3(t) do { const __hip_bfloat16* gg = Bbase + (t) * 64; \
        char* dd = lds + ((t) & 1) * 32768 + 16384 + ldsw; \
        gload_lds16(gg + arow, dd); gload_lds16(gg + arow + (size_t)32 * lda, dd + 4096); } while (0)
#define STQ4(t) do { const __hip_bfloat16* gg = Bbase + (t) * 64 + (size_t)64 * lda; \
        char* dd = lds + ((t) & 1) * 32768 + 24576 + ldsw; \
        gload_lds16(gg + arow, dd); gload_lds16(gg + arow + (size_t)32 * lda, dd + 4096); } while (0)

#define MFMA_N(n0) do { \
        _Pragma("unroll") \
        for (int mi = 0; mi < 4; mi++) \
            _Pragma("unroll") \
            for (int nn = (n0); nn < (n0) + 2; nn++) { \
                acc[mi][nn] = __builtin_amdgcn_mfma_f32_16x16x32_bf16(af[mi][0], bf[nn][0], acc[mi][nn], 0, 0, 0); \
                acc[mi][nn] = __builtin_amdgcn_mfma_f32_16x16x32_bf16(af[mi][1], bf[nn][1], acc[mi][nn], 0, 0, 0); \
            } } while (0)

    STQ1(0); STQ2(0); STQ3(0); STQ4(0);
    STQ2(1); STQ3(1); STQ4(1);
    asm volatile("s_waitcnt vmcnt(6)" ::: "memory");
    __builtin_amdgcn_s_barrier();

    short8 af[4][2], bf[4][2];
    for (int t = 0; t < nt; ++t) {
        int d = (t & 1) * 32768;

        #pragma unroll
        for (int mi = 0; mi < 4; mi++) {
            af[mi][0] = *(const short8*)(lds + d + aoff + mi * 2048 + rc0);
            af[mi][1] = *(const short8*)(lds + d + aoff + mi * 2048 + rc1);
        }
        #pragma unroll
        for (int ni = 0; ni < 4; ni++) {
            bf[ni][0] = *(const short8*)(lds + d + boff + ni * 2048 + rc0);
            bf[ni][1] = *(const short8*)(lds + d + boff + ni * 2048 + rc1);
        }
        if (t + 1 < nt) STQ1(t + 1);
        __builtin_amdgcn_s_barrier();
        __builtin_amdgcn_s_setprio(1);
        MFMA_N(0);
        __builtin_amdgcn_s_setprio(0);

        if (t + 2 < nt) { STQ2(t + 2); STQ3(t + 2); STQ4(t + 2); }
        if (t < nt - 2) asm volatile("s_waitcnt vmcnt(6)" ::: "memory");
        else            asm volatile("s_waitcnt vmcnt(0)" ::: "memory");
        __builtin_amdgcn_s_barrier();
        __builtin_amdgcn_s_setprio(1);
        MFMA_N(2);
        __builtin_amdgcn_s_setprio(0);
    }

    int rq = lane >> 4, cl = lane & 15;
    #pragma unroll
    for (int mi = 0; mi < 4; mi++) {
        #pragma unroll
        for (int ni = 0; ni < 4; ni++) {
            int col = bx * 128 + wc * 64 + ni * 16 + cl;
            #pragma unroll
            for (int j = 0; j < 4; j++) {
                int row = by * 128 + wr * 64 + mi * 16 + rq * 4 + j;
                Cz[(size_t)row * ldc + col] = acc[mi][ni][j];
            }
        }
    }
#undef STQ1
#undef STQ2
#undef STQ3
#undef STQ4
#undef MFMA_N
}

// ---------------- persistent 256x256 decoder GEMM, 2 merged phases / 2 barriers ----------------
// R13 change: ALL WRQ stores moved after phase B's vmcnt+BAR+MFMA_B, so the counted
// vmcnt(6) never eagerly drains them; they retire during the next tile's phase A
// (~2500cy) and are forced complete only at phase B(v+1)'s vmcnt — by then free.
// Ledger unchanged: stores add no guarantee requirement; acc reset still precedes
// the next tile's MFMA_A in program order. BAR_A remains (load-bearing, R11).
#define KTILES 12
#define TPB 4
#define VTOT (KTILES * TPB)
__global__ __launch_bounds__(512, 2) void gemm256p(const __hip_bfloat16* __restrict__ A,
                                                   const __hip_bfloat16* __restrict__ Bt,
                                                   float* __restrict__ C,
                                                   int K, int Nvalid,
                                                   const float* __restrict__ bias, int ldc) {
    __shared__ char lds[131072];
    int h = blockIdx.x;
    int chunk = gridDim.x >> 3;               // 30
    int l = (h & 7) * chunk + (h >> 3);
    int bn = l >> 1;
    int bm0 = (l & 1) * 4;

    int tid = threadIdx.x;
    int lane = tid & 63;
    int w = tid >> 6;
    int wr = w >> 2, wc = w & 3;

    int r0 = tid >> 3;
    int swz8 = (((tid & 7) ^ (r0 & 7)) << 3);
    const __hip_bfloat16* Bbase = Bt + (size_t)(bn * 256) * K;
    size_t arow0 = (size_t)r0 * K + swz8;
    size_t arow1 = arow0 + (size_t)64 * K;
    int ldsw = tid * 16;

    int rxor = (lane & 7) << 4;
    int rcol = ((lane >> 4) & 3) * 16;
    int rc0 = (0 + rcol) ^ rxor;
    int rc1 = (64 + rcol) ^ rxor;
    int aoff = (wr * 64 + (lane & 15)) * 128;
    int boff = 32768 + (wc * 32 + (lane & 15)) * 128;

    int rq = lane >> 4, cl = lane & 15;
    float bv[2][2];
    #pragma unroll
    for (int qn = 0; qn < 2; qn++)
        #pragma unroll
        for (int ni = 0; ni < 2; ni++) {
            int col = bn * 256 + qn * 128 + wc * 32 + ni * 16 + cl;
            bv[qn][ni] = (col < Nvalid) ? bias[col] : 0.f;
        }

    f32x4 acc[2][2][4][2] = {};

#define ABASE(va) (A + (size_t)((bm0 + (va) / KTILES) * 256) * K)
#define KKOF(va)  (((va) % KTILES) * 64)
#define STAGEA(va, half) do { \
        const __hip_bfloat16* gg = ABASE(va) + (size_t)(half) * 128 * K + KKOF(va); \
        char* dd = lds + ((va) & 1) * 65536 + (half) * 16384 + ldsw; \
        gload_lds16(gg + arow0, dd); \
        gload_lds16(gg + arow1, dd + 8192); } while (0)
#define STAGEB(va, half) do { \
        const __hip_bfloat16* gg = Bbase + (size_t)(half) * 128 * K + KKOF(va); \
        char* dd = lds + ((va) & 1) * 65536 + 32768 + (half) * 16384 + ldsw; \
        gload_lds16(gg + arow0, dd); \
        gload_lds16(gg + arow1, dd + 8192); } while (0)

#define MFMA_Q(qm, qn, AF, BF) do { \
        _Pragma("unroll") \
        for (int mi = 0; mi < 4; mi++) \
            _Pragma("unroll") \
            for (int ni = 0; ni < 2; ni++) { \
                acc[qm][qn][mi][ni] = __builtin_amdgcn_mfma_f32_16x16x32_bf16(AF[mi][0], BF[ni][0], acc[qm][qn][mi][ni], 0, 0, 0); \
                acc[qm][qn][mi][ni] = __builtin_amdgcn_mfma_f32_16x16x32_bf16(AF[mi][1], BF[ni][1], acc[qm][qn][mi][ni], 0, 0, 0); \
            } } while (0)

#define WRQ(qm, qn) do { \
        int bmw = bm0 + v / KTILES; \
        _Pragma("unroll") \
        for (int mi = 0; mi < 4; mi++) \
            _Pragma("unroll") \
            for (int ni = 0; ni < 2; ni++) { \
                int col = bn * 256 + (qn) * 128 + wc * 32 + ni * 16 + cl; \
                if (col < Nvalid) { \
                    _Pragma("unroll") \
                    for (int j = 0; j < 4; j++) { \
                        int row = bmw * 256 + (qm) * 128 + wr * 64 + mi * 16 + rq * 4 + j; \
                        C[(size_t)row * ldc + col] = acc[qm][qn][mi][ni][j] + bv[qn][ni]; \
                    } \
                } \
                acc[qm][qn][mi][ni] = (f32x4){0.f, 0.f, 0.f, 0.f}; \
            } } while (0)

#define BAR() __builtin_amdgcn_s_barrier()

    STAGEA(0, 0); STAGEB(0, 0); STAGEB(0, 1); STAGEA(0, 1);
    STAGEA(1, 0); STAGEB(1, 0); STAGEB(1, 1);
    asm volatile("s_waitcnt vmcnt(6)" ::: "memory");
    BAR();

    short8 af0[4][2], af1[4][2], bf0[2][2], bf1[2][2];
    for (int v = 0; v < VTOT; ++v) {
        int d = (v & 1) * 65536;
        bool last = ((v % KTILES) == KTILES - 1);

        #pragma unroll
        for (int mi = 0; mi < 4; mi++) {
            af0[mi][0] = *(const short8*)(lds + d + aoff + mi * 2048 + rc0);
            af0[mi][1] = *(const short8*)(lds + d + aoff + mi * 2048 + rc1);
        }
        #pragma unroll
        for (int ni = 0; ni < 2; ni++) {
            bf0[ni][0] = *(const short8*)(lds + d + boff + ni * 2048 + rc0);
            bf0[ni][1] = *(const short8*)(lds + d + boff + ni * 2048 + rc1);
            bf1[ni][0] = *(const short8*)(lds + d + boff + 16384 + ni * 2048 + rc0);
            bf1[ni][1] = *(const short8*)(lds + d + boff + 16384 + ni * 2048 + rc1);
        }
        #pragma unroll
        for (int mi = 0; mi < 4; mi++) {
            af1[mi][0] = *(const short8*)(lds + d + 16384 + aoff + mi * 2048 + rc0);
            af1[mi][1] = *(const short8*)(lds + d + 16384 + aoff + mi * 2048 + rc1);
        }
        if (v + 1 < VTOT) STAGEA(v + 1, 1);
        BAR();
        __builtin_amdgcn_s_setprio(1);
        MFMA_Q(0, 0, af0, bf0);
        MFMA_Q(0, 1, af0, bf1);
        __builtin_amdgcn_s_setprio(0);

        if (v + 2 < VTOT) { STAGEA(v + 2, 0); STAGEB(v + 2, 0); STAGEB(v + 2, 1); }
        if (v < VTOT - 2) asm volatile("s_waitcnt vmcnt(6)" ::: "memory");
        else              asm volatile("s_waitcnt vmcnt(0)" ::: "memory");
        BAR();
        __builtin_amdgcn_s_setprio(1);
        MFMA_Q(1, 1, af1, bf1);
        MFMA_Q(1, 0, af1, bf0);
        __builtin_amdgcn_s_setprio(0);
        // all C-writes AFTER the counted vmcnt: stores retire during next tile's phase A
        if (last) { WRQ(0, 0); WRQ(0, 1); WRQ(1, 1); WRQ(1, 0); }
    }
#undef STAGEA
#undef STAGEB
#undef MFMA_Q
#undef WRQ
#undef BAR
#undef ABASE
#undef KKOF
}

extern "C" void kernel_launch(void* const* d_in, const int* in_sizes, int n_in,
                              void* d_out, int out_size, void* d_ws, size_t ws_size,
                              hipStream_t stream) {
    const float* hidden = (const float*)d_in[0];
    const int*   span   = (const int*)d_in[1];
    const float* pe     = (const float*)d_in[2];
    const float* W1     = (const float*)d_in[3];
    const float* b1     = (const float*)d_in[4];
    const float* g1     = (const float*)d_in[5];
    const float* be1    = (const float*)d_in[6];
    const float* W2     = (const float*)d_in[7];
    const float* b2     = (const float*)d_in[8];
    const float* g2     = (const float*)d_in[9];
    const float* be2    = (const float*)d_in[10];
    const float* Wdec   = (const float*)d_in[11];
    const float* dbias  = (const float*)d_in[12];
    float* out = (float*)d_out;

    const int M = BSZ * SEQ;  // 2048
    char* ws = (char*)d_ws;
    size_t off = 0;
    int* fw = (int*)(ws + off);                 off += (size_t)M * 4;
    int* bw = (int*)(ws + off);                 off += (size_t)M * 4;
    __hip_bfloat16* Xb   = (__hip_bfloat16*)(ws + off); off += (size_t)M * 3 * HID * 2;
    __hip_bfloat16* W1t  = (__hip_bfloat16*)(ws + off); off += (size_t)HID * 3 * HID * 2;
    __hip_bfloat16* W2t  = (__hip_bfloat16*)(ws + off); off += (size_t)HID * HID * 2;
    __hip_bfloat16* Wdt  = (__hip_bfloat16*)(ws + off); off += (size_t)NPAD * HID * 2;
    float* Y             = (float*)(ws + off);          off += (size_t)M * HID * 4 * 4;
    __hip_bfloat16* mid  = (__hip_bfloat16*)(ws + off); off += (size_t)M * HID * 2;
    __hip_bfloat16* pre  = (__hip_bfloat16*)(ws + off); off += (size_t)M * HID * 2;
    size_t ystride = (size_t)M * HID;

    // 1. span scans
    scan_kernel<<<BSZ, SEQ, 0, stream>>>(span, fw, bw);
    // 2. merged: build X + all transposes
    prep_all<<<BX_BLOCKS + T1_TILES + T2_TILES + TD_TILES, 256, 0, stream>>>(
        hidden, span, pe, fw, bw, Xb, W1, W1t, W2, W2t, Wdec, Wdt);
    // 3. GEMM1 (split-K x4, 2-phase)
    gemm_splitk<<<dim3(HID / 128, M / 128, 4), 256, 0, stream>>>(Xb, W1t, Y, 3 * HID, 3 * HID / 4, HID, ystride);
    // 4. sum4+bias, gelu, LN -> mid
    gelu_ln<4><<<M, 256, 0, stream>>>(Y, ystride, b1, g1, be1, mid);
    // 5. GEMM2 (split-K x2, 2-phase)
    gemm_splitk<<<dim3(HID / 128, M / 128, 2), 256, 0, stream>>>(mid, W2t, Y, HID, HID / 2, HID, ystride);
    // 6. sum2+bias, gelu, LN -> pre
    gelu_ln<2><<<M, 256, 0, stream>>>(Y, ystride, b2, g2, be2, pre);
    // 7. decoder GEMM: persistent 256^2, 2-barrier phases, deferred store-drain, grid 240
    gemm256p<<<240, 512, 0, stream>>>(pre, Wdt, out, HID, VOC, dbias, VOC);
}

// Round 14
// 209.306 us; speedup vs baseline: 1.0200x; 1.0200x over previous
//
#include <hip/hip_runtime.h>
#include <hip/hip_bf16.h>

#define BSZ 4
#define SEQ 512
#define HID 768
#define VOC 30522
#define NPAD 30720

typedef __attribute__((ext_vector_type(8))) short short8;
typedef __attribute__((ext_vector_type(4))) float f32x4;

typedef const unsigned int __attribute__((address_space(1)))* gptr_t;
typedef unsigned int __attribute__((address_space(3)))* lptr_t;

__device__ __forceinline__ void gload_lds16(const void* g, void* l) {
    __builtin_amdgcn_global_load_lds((gptr_t)g, (lptr_t)l, 16, 0, 0);
}

// ---------------- span scans ----------------
__global__ __launch_bounds__(512) void scan_kernel(const int* __restrict__ span,
                                                   int* __restrict__ fw, int* __restrict__ bw) {
    int b = blockIdx.x;
    int j = threadIdx.x;
    __shared__ int sm[SEQ];
    __shared__ int sc[SEQ];
    int m = (span[b * SEQ + j] > -1) ? 1 : 0;
    sm[j] = m;
    __syncthreads();
    int prev = (j > 0) ? sm[j - 1] : 0;
    int nxt  = (j < SEQ - 1) ? sm[j + 1] : 0;
    int cfw = (m && !prev && j > 0) ? (j - 1) : 0;
    int cbw = (m && !nxt && j < SEQ - 1) ? (j + 1) : (SEQ - 1);

    int v = cfw;
    sc[j] = v; __syncthreads();
    for (int off = 1; off < SEQ; off <<= 1) {
        int o = (j >= off) ? sc[j - off] : 0;
        __syncthreads();
        v = max(v, o);
        sc[j] = v; __syncthreads();
    }
    fw[b * SEQ + j] = v;

    v = cbw;
    sc[j] = v; __syncthreads();
    for (int off = 1; off < SEQ; off <<= 1) {
        int o = (j + off < SEQ) ? sc[j + off] : (SEQ - 1);
        __syncthreads();
        v = min(v, o);
        sc[j] = v; __syncthreads();
    }
    bw[b * SEQ + j] = v;
}

// ---------------- merged prep: build_x (blocks 0..2047) + all transposes (rest) ----------------
#define T1_TILES (12 * 36)
#define T2_TILES (12 * 12)
#define TD_TILES (480 * 12)
#define BX_BLOCKS (BSZ * SEQ)
__global__ __launch_bounds__(256) void prep_all(const float* __restrict__ h,
                                                const int* __restrict__ span,
                                                const float* __restrict__ pe,
                                                const int* __restrict__ fw,
                                                const int* __restrict__ bw,
                                                __hip_bfloat16* __restrict__ X,
                                                const float* __restrict__ W1, __hip_bfloat16* __restrict__ W1t,
                                                const float* __restrict__ W2, __hip_bfloat16* __restrict__ W2t,
                                                const float* __restrict__ Wd, __hip_bfloat16* __restrict__ Wdt) {
    if (blockIdx.x < BX_BLOCKS) {
        int r = blockIdx.x;
        int b = r >> 9, s = r & (SEQ - 1);
        float mf = (span[r] > -1) ? 1.f : 0.f;
        int f = fw[r], w = bw[r];
        const float* hf = h + ((size_t)b * SEQ + f) * HID;
        const float* hb = h + ((size_t)b * SEQ + w) * HID;
        const float* pp = pe + (size_t)s * HID;
        __hip_bfloat16* xr = X + (size_t)r * (3 * HID);
        for (int u = threadIdx.x; u < 3 * HID / 2; u += 256) {
            int seg = u / (HID / 2);
            int c = (u % (HID / 2)) * 2;
            const float* src = (seg == 0) ? hf : (seg == 1) ? hb : pp;
            float2 v = *(const float2*)&src[c];
            __hip_bfloat16 lo = __float2bfloat16(v.x * mf);
            __hip_bfloat16 hi = __float2bfloat16(v.y * mf);
            unsigned int pk = ((unsigned int)*(unsigned short*)&hi << 16) | *(unsigned short*)&lo;
            *(unsigned int*)&xr[seg * HID + c] = pk;
        }
        return;
    }
    int flat = blockIdx.x - BX_BLOCKS;
    const float* W; __hip_bfloat16* Wt; int K, N, tx_tiles, idx;
    if (flat < T1_TILES)                { W = W1; Wt = W1t; K = 3 * HID; N = HID; tx_tiles = 12;  idx = flat; }
    else if (flat < T1_TILES + T2_TILES){ W = W2; Wt = W2t; K = HID;     N = HID; tx_tiles = 12;  idx = flat - T1_TILES; }
    else                                { W = Wd; Wt = Wdt; K = HID;     N = VOC; tx_tiles = 480; idx = flat - T1_TILES - T2_TILES; }
    int n0 = (idx % tx_tiles) * 64, k0 = (idx / tx_tiles) * 64;

    __shared__ float t[64][67];
    int tx = threadIdx.x & 31, ty = threadIdx.x >> 5;
    #pragma unroll
    for (int i = 0; i < 64; i += 8) {
        #pragma unroll
        for (int jx = 0; jx < 64; jx += 32) {
            int k = k0 + ty + i, n = n0 + tx + jx;
            t[ty + i][tx + jx] = (n < N) ? W[(size_t)k * N + n] : 0.f;
        }
    }
    __syncthreads();
    #pragma unroll
    for (int i = 0; i < 8; i++) {
        int nn = ty + i * 8;
        int n = n0 + nn;
        float a = t[tx * 2][nn], b = t[tx * 2 + 1][nn];
        __hip_bfloat16 ba = __float2bfloat16(a), bb = __float2bfloat16(b);
        unsigned int pk = ((unsigned int)*(unsigned short*)&bb << 16) | *(unsigned short*)&ba;
        *(unsigned int*)&Wt[(size_t)n * K + k0 + tx * 2] = pk;
    }
}

// ---------------- sum(P split-K parts)+bias, exact gelu, layernorm -> bf16 ----------------
template<int P>
__global__ __launch_bounds__(256) void gelu_ln(const float* __restrict__ Y, size_t ystride,
                                               const float* __restrict__ bias,
                                               const float* __restrict__ g,
                                               const float* __restrict__ be,
                                               __hip_bfloat16* __restrict__ out) {
    int r = blockIdx.x;
    float z[3];
    float s1 = 0.f, s2 = 0.f;
    #pragma unroll
    for (int i = 0; i < 3; i++) {
        int c = threadIdx.x + i * 256;
        float x = bias[c];
        #pragma unroll
        for (int p = 0; p < P; p++)
            x += Y[p * ystride + (size_t)r * HID + c];
        float zz = 0.5f * x * (1.f + erff(x * 0.70710678118654752f));
        z[i] = zz; s1 += zz; s2 += zz * zz;
    }
    #pragma unroll
    for (int off = 32; off; off >>= 1) {
        s1 += __shfl_down(s1, off);
        s2 += __shfl_down(s2, off);
    }
    __shared__ float p1[4], p2[4];
    int w = threadIdx.x >> 6, lane = threadIdx.x & 63;
    if (lane == 0) { p1[w] = s1; p2[w] = s2; }
    __syncthreads();
    s1 = p1[0] + p1[1] + p1[2] + p1[3];
    s2 = p2[0] + p2[1] + p2[2] + p2[3];
    float mu = s1 * (1.f / HID);
    float var = s2 * (1.f / HID) - mu * mu;
    float rs = rsqrtf(var + 1e-12f);
    __hip_bfloat16* o = out + (size_t)r * HID;
    #pragma unroll
    for (int i = 0; i < 3; i++) {
        int c = threadIdx.x + i * 256;
        o[c] = __float2bfloat16((z[i] - mu) * rs * g[c] + be[c]);
    }
}

// ---------------- 128x128 split-K GEMM, 2-phase schedule (R10 exact) ----------------
__global__ __launch_bounds__(256, 2) void gemm_splitk(const __hip_bfloat16* __restrict__ A,
                                                      const __hip_bfloat16* __restrict__ Bt,
                                                      float* __restrict__ C,
                                                      int lda, int Klen, int ldc, size_t cstride) {
    __shared__ char lds[65536];
    int bx = blockIdx.x, by = blockIdx.y;
    int koff = blockIdx.z * Klen;
    float* Cz = C + (size_t)blockIdx.z * cstride;

    int tid = threadIdx.x;
    int lane = tid & 63;
    int w = tid >> 6;
    int wr = w >> 1, wc = w & 1;

    int r0 = tid >> 3;
    int swz8 = (((tid & 7) ^ (r0 & 7)) << 3);
    const __hip_bfloat16* Abase = A + (size_t)(by * 128) * lda + koff;
    const __hip_bfloat16* Bbase = Bt + (size_t)(bx * 128) * lda + koff;
    size_t arow = (size_t)r0 * lda + swz8;
    int ldsw = tid * 16;

    int rxor = (lane & 7) << 4;
    int rcol = (lane >> 4) * 16;
    int rc0 = rcol ^ rxor;
    int rc1 = (64 + rcol) ^ rxor;
    int aoff = (wr * 64 + (lane & 15)) * 128;
    int boff = 16384 + (wc * 64 + (lane & 15)) * 128;

    f32x4 acc[4][4] = {};
    int nt = Klen >> 6;

#define STQ1(t) do { const __hip_bfloat16* gg = Abase + (t) * 64; \
        char* dd = lds + ((t) & 1) * 32768 + ldsw; \
        gload_lds16(gg + arow, dd); gload_lds16(gg + arow + (size_t)32 * lda, dd + 4096); } while (0)
#define STQ2(t) do { const __hip_bfloat16* gg = Abase + (t) * 64 + (size_t)64 * lda; \
        char* dd = lds + ((t) & 1) * 32768 + 8192 + ldsw; \
        gload_lds16(gg + arow, dd); gload_lds16(gg + arow + (size_t)32 * lda, dd + 4096); } while (0)
#define STQ3(t) do { const __hip_bfloat16* gg = Bbase + (t) * 64; \
        char* dd = lds + ((t) & 1) * 32768 + 16384 + ldsw; \
        gload_lds16(gg + arow, dd); gload_lds16(gg + arow + (size_t)32 * lda, dd + 4096); } while (0)
#define STQ4(t) do { const __hip_bfloat16* gg = Bbase + (t) * 64 + (size_t)64 * lda; \
        char* dd = lds + ((t) & 1) * 32768 + 24576 + ldsw; \
        gload_lds16(gg + arow, dd); gload_lds16(gg + arow + (size_t)32 * lda, dd + 4096); } while (0)

#define MFMA_N(n0) do { \
        _Pragma("unroll") \
        for (int mi = 0; mi < 4; mi++) \
            _Pragma("unroll") \
            for (int nn = (n0); nn < (n0) + 2; nn++) { \
                acc[mi][nn] = __builtin_amdgcn_mfma_f32_16x16x32_bf16(af[mi][0], bf[nn][0], acc[mi][nn], 0, 0, 0); \
                acc[mi][nn] = __builtin_amdgcn_mfma_f32_16x16x32_bf16(af[mi][1], bf[nn][1], acc[mi][nn], 0, 0, 0); \
            } } while (0)

    STQ1(0); STQ2(0); STQ3(0); STQ4(0);
    STQ2(1); STQ3(1); STQ4(1);
    asm volatile("s_waitcnt vmcnt(6)" ::: "memory");
    __builtin_amdgcn_s_barrier();

    short8 af[4][2], bf[4][2];
    for (int t = 0; t < nt; ++t) {
        int d = (t & 1) * 32768;

        #pragma unroll
        for (int mi = 0; mi < 4; mi++) {
            af[mi][0] = *(const short8*)(lds + d + aoff + mi * 2048 + rc0);
            af[mi][1] = *(const short8*)(lds + d + aoff + mi * 2048 + rc1);
        }
        #pragma unroll
        for (int ni = 0; ni < 4; ni++) {
            bf[ni][0] = *(const short8*)(lds + d + boff + ni * 2048 + rc0);
            bf[ni][1] = *(const short8*)(lds + d + boff + ni * 2048 + rc1);
        }
        if (t + 1 < nt) STQ1(t + 1);
        __builtin_amdgcn_s_barrier();
        __builtin_amdgcn_s_setprio(1);
        MFMA_N(0);
        __builtin_amdgcn_s_setprio(0);

        if (t + 2 < nt) { STQ2(t + 2); STQ3(t + 2); STQ4(t + 2); }
        if (t < nt - 2) asm volatile("s_waitcnt vmcnt(6)" ::: "memory");
        else            asm volatile("s_waitcnt vmcnt(0)" ::: "memory");
        __builtin_amdgcn_s_barrier();
        __builtin_amdgcn_s_setprio(1);
        MFMA_N(2);
        __builtin_amdgcn_s_setprio(0);
    }

    int rq = lane >> 4, cl = lane & 15;
    #pragma unroll
    for (int mi = 0; mi < 4; mi++) {
        #pragma unroll
        for (int ni = 0; ni < 4; ni++) {
            int col = bx * 128 + wc * 64 + ni * 16 + cl;
            #pragma unroll
            for (int j = 0; j < 4; j++) {
                int row = by * 128 + wr * 64 + mi * 16 + rq * 4 + j;
                Cz[(size_t)row * ldc + col] = acc[mi][ni][j];
            }
        }
    }
#undef STQ1
#undef STQ2
#undef STQ3
#undef STQ4
#undef MFMA_N
}

// ---------------- persistent 256x256 decoder GEMM, 2 merged phases / 2 barriers (R12 exact) ----------------
// BAR_A is LOAD-BEARING (R11 removal raced). WRQ placement per-phase (R12) — R13's
// deferred-store variant was slightly worse (store burst delayed next-tile reads).
#define KTILES 12
#define TPB 4
#define VTOT (KTILES * TPB)
__global__ __launch_bounds__(512, 2) void gemm256p(const __hip_bfloat16* __restrict__ A,
                                                   const __hip_bfloat16* __restrict__ Bt,
                                                   float* __restrict__ C,
                                                   int K, int Nvalid,
                                                   const float* __restrict__ bias, int ldc) {
    __shared__ char lds[131072];
    int h = blockIdx.x;
    int chunk = gridDim.x >> 3;               // 30
    int l = (h & 7) * chunk + (h >> 3);
    int bn = l >> 1;
    int bm0 = (l & 1) * 4;

    int tid = threadIdx.x;
    int lane = tid & 63;
    int w = tid >> 6;
    int wr = w >> 2, wc = w & 3;

    int r0 = tid >> 3;
    int swz8 = (((tid & 7) ^ (r0 & 7)) << 3);
    const __hip_bfloat16* Bbase = Bt + (size_t)(bn * 256) * K;
    size_t arow0 = (size_t)r0 * K + swz8;
    size_t arow1 = arow0 + (size_t)64 * K;
    int ldsw = tid * 16;

    int rxor = (lane & 7) << 4;
    int rcol = ((lane >> 4) & 3) * 16;
    int rc0 = (0 + rcol) ^ rxor;
    int rc1 = (64 + rcol) ^ rxor;
    int aoff = (wr * 64 + (lane & 15)) * 128;
    int boff = 32768 + (wc * 32 + (lane & 15)) * 128;

    int rq = lane >> 4, cl = lane & 15;
    float bv[2][2];
    #pragma unroll
    for (int qn = 0; qn < 2; qn++)
        #pragma unroll
        for (int ni = 0; ni < 2; ni++) {
            int col = bn * 256 + qn * 128 + wc * 32 + ni * 16 + cl;
            bv[qn][ni] = (col < Nvalid) ? bias[col] : 0.f;
        }

    f32x4 acc[2][2][4][2] = {};

#define ABASE(va) (A + (size_t)((bm0 + (va) / KTILES) * 256) * K)
#define KKOF(va)  (((va) % KTILES) * 64)
#define STAGEA(va, half) do { \
        const __hip_bfloat16* gg = ABASE(va) + (size_t)(half) * 128 * K + KKOF(va); \
        char* dd = lds + ((va) & 1) * 65536 + (half) * 16384 + ldsw; \
        gload_lds16(gg + arow0, dd); \
        gload_lds16(gg + arow1, dd + 8192); } while (0)
#define STAGEB(va, half) do { \
        const __hip_bfloat16* gg = Bbase + (size_t)(half) * 128 * K + KKOF(va); \
        char* dd = lds + ((va) & 1) * 65536 + 32768 + (half) * 16384 + ldsw; \
        gload_lds16(gg + arow0, dd); \
        gload_lds16(gg + arow1, dd + 8192); } while (0)

#define MFMA_Q(qm, qn, AF, BF) do { \
        _Pragma("unroll") \
        for (int mi = 0; mi < 4; mi++) \
            _Pragma("unroll") \
            for (int ni = 0; ni < 2; ni++) { \
                acc[qm][qn][mi][ni] = __builtin_amdgcn_mfma_f32_16x16x32_bf16(AF[mi][0], BF[ni][0], acc[qm][qn][mi][ni], 0, 0, 0); \
                acc[qm][qn][mi][ni] = __builtin_amdgcn_mfma_f32_16x16x32_bf16(AF[mi][1], BF[ni][1], acc[qm][qn][mi][ni], 0, 0, 0); \
            } } while (0)

#define WRQ(qm, qn) do { \
        int bmw = bm0 + v / KTILES; \
        _Pragma("unroll") \
        for (int mi = 0; mi < 4; mi++) \
            _Pragma("unroll") \
            for (int ni = 0; ni < 2; ni++) { \
                int col = bn * 256 + (qn) * 128 + wc * 32 + ni * 16 + cl; \
                if (col < Nvalid) { \
                    _Pragma("unroll") \
                    for (int j = 0; j < 4; j++) { \
                        int row = bmw * 256 + (qm) * 128 + wr * 64 + mi * 16 + rq * 4 + j; \
                        C[(size_t)row * ldc + col] = acc[qm][qn][mi][ni][j] + bv[qn][ni]; \
                    } \
                } \
                acc[qm][qn][mi][ni] = (f32x4){0.f, 0.f, 0.f, 0.f}; \
            } } while (0)

#define BAR() __builtin_amdgcn_s_barrier()

    STAGEA(0, 0); STAGEB(0, 0); STAGEB(0, 1); STAGEA(0, 1);
    STAGEA(1, 0); STAGEB(1, 0); STAGEB(1, 1);
    asm volatile("s_waitcnt vmcnt(6)" ::: "memory");
    BAR();

    short8 af0[4][2], af1[4][2], bf0[2][2], bf1[2][2];
    for (int v = 0; v < VTOT; ++v) {
        int d = (v & 1) * 65536;
        bool last = ((v % KTILES) == KTILES - 1);

        #pragma unroll
        for (int mi = 0; mi < 4; mi++) {
            af0[mi][0] = *(const short8*)(lds + d + aoff + mi * 2048 + rc0);
            af0[mi][1] = *(const short8*)(lds + d + aoff + mi * 2048 + rc1);
        }
        #pragma unroll
        for (int ni = 0; ni < 2; ni++) {
            bf0[ni][0] = *(const short8*)(lds + d + boff + ni * 2048 + rc0);
            bf0[ni][1] = *(const short8*)(lds + d + boff + ni * 2048 + rc1);
            bf1[ni][0] = *(const short8*)(lds + d + boff + 16384 + ni * 2048 + rc0);
            bf1[ni][1] = *(const short8*)(lds + d + boff + 16384 + ni * 2048 + rc1);
        }
        #pragma unroll
        for (int mi = 0; mi < 4; mi++) {
            af1[mi][0] = *(const short8*)(lds + d + 16384 + aoff + mi * 2048 + rc0);
            af1[mi][1] = *(const short8*)(lds + d + 16384 + aoff + mi * 2048 + rc1);
        }
        if (v + 1 < VTOT) STAGEA(v + 1, 1);
        BAR();
        __builtin_amdgcn_s_setprio(1);
        MFMA_Q(0, 0, af0, bf0);
        MFMA_Q(0, 1, af0, bf1);
        __builtin_amdgcn_s_setprio(0);
        if (last) { WRQ(0, 0); WRQ(0, 1); }

        if (v + 2 < VTOT) { STAGEA(v + 2, 0); STAGEB(v + 2, 0); STAGEB(v + 2, 1); }
        if (v < VTOT - 2) asm volatile("s_waitcnt vmcnt(6)" ::: "memory");
        else              asm volatile("s_waitcnt vmcnt(0)" ::: "memory");
        BAR();
        __builtin_amdgcn_s_setprio(1);
        MFMA_Q(1, 1, af1, bf1);
        MFMA_Q(1, 0, af1, bf0);
        __builtin_amdgcn_s_setprio(0);
        if (last) { WRQ(1, 1); WRQ(1, 0); }
    }
#undef STAGEA
#undef STAGEB
#undef MFMA_Q
#undef WRQ
#undef BAR
#undef ABASE
#undef KKOF
}

extern "C" void kernel_launch(void* const* d_in, const int* in_sizes, int n_in,
                              void* d_out, int out_size, void* d_ws, size_t ws_size,
                              hipStream_t stream) {
    const float* hidden = (const float*)d_in[0];
    const int*   span   = (const int*)d_in[1];
    const float* pe     = (const float*)d_in[2];
    const float* W1     = (const float*)d_in[3];
    const float* b1     = (const float*)d_in[4];
    const float* g1     = (const float*)d_in[5];
    const float* be1    = (const float*)d_in[6];
    const float* W2     = (const float*)d_in[7];
    const float* b2     = (const float*)d_in[8];
    const float* g2     = (const float*)d_in[9];
    const float* be2    = (const float*)d_in[10];
    const float* Wdec   = (const float*)d_in[11];
    const float* dbias  = (const float*)d_in[12];
    float* out = (float*)d_out;

    const int M = BSZ * SEQ;  // 2048
    char* ws = (char*)d_ws;
    size_t off = 0;
    int* fw = (int*)(ws + off);                 off += (size_t)M * 4;
    int* bw = (int*)(ws + off);                 off += (size_t)M * 4;
    __hip_bfloat16* Xb   = (__hip_bfloat16*)(ws + off); off += (size_t)M * 3 * HID * 2;
    __hip_bfloat16* W1t  = (__hip_bfloat16*)(ws + off); off += (size_t)HID * 3 * HID * 2;
    __hip_bfloat16* W2t  = (__hip_bfloat16*)(ws + off); off += (size_t)HID * HID * 2;
    __hip_bfloat16* Wdt  = (__hip_bfloat16*)(ws + off); off += (size_t)NPAD * HID * 2;
    float* Y             = (float*)(ws + off);          off += (size_t)M * HID * 4 * 4;
    __hip_bfloat16* mid  = (__hip_bfloat16*)(ws + off); off += (size_t)M * HID * 2;
    __hip_bfloat16* pre  = (__hip_bfloat16*)(ws + off); off += (size_t)M * HID * 2;
    size_t ystride = (size_t)M * HID;

    // 1. span scans
    scan_kernel<<<BSZ, SEQ, 0, stream>>>(span, fw, bw);
    // 2. merged: build X + all transposes
    prep_all<<<BX_BLOCKS + T1_TILES + T2_TILES + TD_TILES, 256, 0, stream>>>(
        hidden, span, pe, fw, bw, Xb, W1, W1t, W2, W2t, Wdec, Wdt);
    // 3. GEMM1 (split-K x4, 2-phase)
    gemm_splitk<<<dim3(HID / 128, M / 128, 4), 256, 0, stream>>>(Xb, W1t, Y, 3 * HID, 3 * HID / 4, HID, ystride);
    // 4. sum4+bias, gelu, LN -> mid
    gelu_ln<4><<<M, 256, 0, stream>>>(Y, ystride, b1, g1, be1, mid);
    // 5. GEMM2 (split-K x2, 2-phase)
    gemm_splitk<<<dim3(HID / 128, M / 128, 2), 256, 0, stream>>>(mid, W2t, Y, HID, HID / 2, HID, ystride);
    // 6. sum2+bias, gelu, LN -> pre
    gelu_ln<2><<<M, 256, 0, stream>>>(Y, ystride, b2, g2, be2, pre);
    // 7. decoder GEMM: persistent 256^2, 2-barrier merged phases (known-good), grid 240
    gemm256p<<<240, 512, 0, stream>>>(pre, Wdt, out, HID, VOC, dbias, VOC);
}